// Round 1
// baseline (1897.531 us; speedup 1.0000x reference)
//
#include <hip/hip_runtime.h>
#include <math.h>

// Problem constants (B=8, T=2048, E=256, H=8, D=32, F=4E=1024)
#define TB 8
#define TT 2048
#define TE 256
#define TH 8
#define TD 32
#define TF 1024
#define NTOK (TB * TT)          // 16384
#define SCALE (1.0f / 16.0f)    // E^-0.5 = 256^-0.5

// ---------------------------------------------------------------------------
// Pack wq/wk/wv (H,E,D) into a (E=256) x (768) row-major weight: col = which*256 + h*32 + d
__global__ __launch_bounds__(256) void pack_w_k(const float* __restrict__ wq,
                                                const float* __restrict__ wk,
                                                const float* __restrict__ wv,
                                                float* __restrict__ wp) {
    int idx = blockIdx.x * 256 + threadIdx.x;   // [0, 256*768)
    int e = idx / 768;
    int col = idx - e * 768;
    int which = col >> 8;
    int r = col & 255;
    int h = r >> 5;
    int d = r & 31;
    const float* w = (which == 0) ? wq : (which == 1) ? wk : wv;
    wp[idx] = w[h * (TE * TD) + e * TD + d];
}

// ---------------------------------------------------------------------------
// LayerNorm over E=256, one block per row
__global__ __launch_bounds__(256) void ln_k(const float* __restrict__ X,
                                            const float* __restrict__ g,
                                            const float* __restrict__ bta,
                                            float* __restrict__ Y) {
    __shared__ float s1[256];
    __shared__ float s2[256];
    int row = blockIdx.x;
    int t = threadIdx.x;
    float v = X[(size_t)row * TE + t];
    s1[t] = v;
    s2[t] = v * v;
    __syncthreads();
    for (int s = 128; s > 0; s >>= 1) {
        if (t < s) { s1[t] += s1[t + s]; s2[t] += s2[t + s]; }
        __syncthreads();
    }
    float mean = s1[0] * (1.0f / TE);
    float var = s2[0] * (1.0f / TE) - mean * mean;
    float rstd = rsqrtf(var + 1e-5f);
    Y[(size_t)row * TE + t] = (v - mean) * rstd * g[t] + bta[t];
}

// ---------------------------------------------------------------------------
// Generic fp32 GEMM: C[M,N] = A[M,K] @ Bw[K,N] (+bias) (+relu) (+resid)
// 64x64 tile, BK=16, 256 threads, 4x4 register tile per thread.
#define BM 64
#define BN 64
#define BK 16
__global__ __launch_bounds__(256) void gemm_k(const float* __restrict__ A,
                                              const float* __restrict__ Bw,
                                              const float* __restrict__ bias,
                                              const float* __restrict__ resid,
                                              float* __restrict__ C,
                                              int M, int N, int K, int relu) {
    __shared__ float As[BK][BM + 4];   // stride 68: float4-aligned, conflict-light
    __shared__ float Bs[BK][BN];
    int tid = threadIdx.x;
    int tx = tid & 15, ty = tid >> 4;
    int m0 = blockIdx.y * BM, n0 = blockIdx.x * BN;
    float acc[4][4] = {};

    for (int k0 = 0; k0 < K; k0 += BK) {
        // A tile: 64 rows x 16 k, one float4 per thread
        {
            int r = tid >> 2;          // 0..63
            int kq = tid & 3;          // 0..3 (x4 floats)
            const float4 v4 = *(const float4*)&A[(size_t)(m0 + r) * K + k0 + kq * 4];
            As[kq * 4 + 0][r] = v4.x;
            As[kq * 4 + 1][r] = v4.y;
            As[kq * 4 + 2][r] = v4.z;
            As[kq * 4 + 3][r] = v4.w;
        }
        // B tile: 16 k x 64 n, one float4 per thread
        {
            int kk = tid >> 4;         // 0..15
            int cq = tid & 15;         // 0..15 (x4 floats)
            const float4 v4 = *(const float4*)&Bw[(size_t)(k0 + kk) * N + n0 + cq * 4];
            Bs[kk][cq * 4 + 0] = v4.x;
            Bs[kk][cq * 4 + 1] = v4.y;
            Bs[kk][cq * 4 + 2] = v4.z;
            Bs[kk][cq * 4 + 3] = v4.w;
        }
        __syncthreads();
#pragma unroll
        for (int kk = 0; kk < BK; ++kk) {
            float4 a4 = *(const float4*)&As[kk][ty * 4];
            float4 b4 = *(const float4*)&Bs[kk][tx * 4];
            float av[4] = {a4.x, a4.y, a4.z, a4.w};
            float bv[4] = {b4.x, b4.y, b4.z, b4.w};
#pragma unroll
            for (int i = 0; i < 4; ++i)
#pragma unroll
                for (int j = 0; j < 4; ++j)
                    acc[i][j] = fmaf(av[i], bv[j], acc[i][j]);
        }
        __syncthreads();
    }

#pragma unroll
    for (int i = 0; i < 4; ++i) {
        size_t row = (size_t)(m0 + ty * 4 + i);
        int col = n0 + tx * 4;
        float4 o;
        o.x = acc[i][0]; o.y = acc[i][1]; o.z = acc[i][2]; o.w = acc[i][3];
        if (bias) {
            o.x += bias[col + 0]; o.y += bias[col + 1];
            o.z += bias[col + 2]; o.w += bias[col + 3];
        }
        if (relu) {
            o.x = fmaxf(o.x, 0.f); o.y = fmaxf(o.y, 0.f);
            o.z = fmaxf(o.z, 0.f); o.w = fmaxf(o.w, 0.f);
        }
        if (resid) {
            const float4 r4 = *(const float4*)&resid[row * N + col];
            o.x += r4.x; o.y += r4.y; o.z += r4.z; o.w += r4.w;
        }
        *(float4*)&C[row * N + col] = o;
    }
}

// ---------------------------------------------------------------------------
// Attention pass 1: per-key-column softmax stats over the QUERY axis.
// Column s: M_s = max_{t>=s} sc[t,s], L_s = sum exp(sc - M_s), sc scaled by 1/16.
// Grid: (T/64 column tiles, B*H). Block 256 = 16x16, 4x4 score tile per thread.
__global__ __launch_bounds__(256) void attn_pass1(const float* __restrict__ qkv,
                                                  float* __restrict__ colM,
                                                  float* __restrict__ colL) {
    __shared__ float Ks[TD][68];   // Ks[d][s_local]
    __shared__ float Qs[TD][68];   // Qs[d][t_local]
    __shared__ float redM[16][64];
    __shared__ float redL[16][64];
    int bh = blockIdx.y;
    int b = bh >> 3, h = bh & 7;
    int s0 = blockIdx.x * 64;
    int tid = threadIdx.x, tx = tid & 15, ty = tid >> 4;

    // Load K tile (transposed) once per block
#pragma unroll
    for (int p = 0; p < 2; ++p) {
        int i4 = tid + p * 256;       // 0..511
        int sl = i4 >> 3;             // 0..63
        int dq = i4 & 7;              // 0..7
        const float4 v4 = *(const float4*)&qkv[((size_t)(b * TT + s0 + sl) * 768) + 256 + h * TD + dq * 4];
        Ks[dq * 4 + 0][sl] = v4.x;
        Ks[dq * 4 + 1][sl] = v4.y;
        Ks[dq * 4 + 2][sl] = v4.z;
        Ks[dq * 4 + 3][sl] = v4.w;
    }

    float m[4], l[4];
#pragma unroll
    for (int j = 0; j < 4; ++j) { m[j] = -INFINITY; l[j] = 0.f; }

    for (int t0 = s0; t0 < TT; t0 += 64) {
        __syncthreads();
#pragma unroll
        for (int p = 0; p < 2; ++p) {
            int i4 = tid + p * 256;
            int tl = i4 >> 3;
            int dq = i4 & 7;
            const float4 v4 = *(const float4*)&qkv[((size_t)(b * TT + t0 + tl) * 768) + h * TD + dq * 4];
            Qs[dq * 4 + 0][tl] = v4.x;
            Qs[dq * 4 + 1][tl] = v4.y;
            Qs[dq * 4 + 2][tl] = v4.z;
            Qs[dq * 4 + 3][tl] = v4.w;
        }
        __syncthreads();

        float sc[4][4] = {};
#pragma unroll
        for (int d = 0; d < TD; ++d) {
            float4 a4 = *(const float4*)&Qs[d][ty * 4];
            float4 b4 = *(const float4*)&Ks[d][tx * 4];
            float av[4] = {a4.x, a4.y, a4.z, a4.w};
            float bv[4] = {b4.x, b4.y, b4.z, b4.w};
#pragma unroll
            for (int i = 0; i < 4; ++i)
#pragma unroll
                for (int j = 0; j < 4; ++j)
                    sc[i][j] = fmaf(av[i], bv[j], sc[i][j]);
        }

        bool edge = (t0 == s0);
#pragma unroll
        for (int j = 0; j < 4; ++j) {
            int sl = tx * 4 + j;
#pragma unroll
            for (int i = 0; i < 4; ++i) {
                int tl = ty * 4 + i;
                if (edge && tl < sl) continue;   // causal: need t >= s
                float v = sc[i][j] * SCALE;
                if (v > m[j]) {
                    l[j] = l[j] * __expf(m[j] - v) + 1.0f;
                    m[j] = v;
                } else {
                    l[j] += __expf(v - m[j]);
                }
            }
        }
    }

    // Reduce the 16 ty-partials per column
#pragma unroll
    for (int j = 0; j < 4; ++j) {
        redM[ty][tx * 4 + j] = m[j];
        redL[ty][tx * 4 + j] = l[j];
    }
    __syncthreads();
    if (tid < 64) {
        float M = -INFINITY;
#pragma unroll
        for (int y = 0; y < 16; ++y) M = fmaxf(M, redM[y][tid]);
        float L = 0.f;
#pragma unroll
        for (int y = 0; y < 16; ++y) L += redL[y][tid] * __expf(redM[y][tid] - M);
        colM[(size_t)bh * TT + s0 + tid] = M;
        colL[(size_t)bh * TT + s0 + tid] = L;
    }
}

// ---------------------------------------------------------------------------
// Attention pass 2: heads[t,d] = sum_{s<=t} exp(sc[t,s]-M_s)/L_s * v[s,d];
// writes xh = xn + heads (residual fused). Grid: (T/64 row tiles, B*H).
__global__ __launch_bounds__(256) void attn_pass2(const float* __restrict__ qkv,
                                                  const float* __restrict__ colM,
                                                  const float* __restrict__ colL,
                                                  const float* __restrict__ xn,
                                                  float* __restrict__ xh) {
    __shared__ float Qs[TD][68];
    __shared__ float Ks[TD][68];
    __shared__ float Vs[64][36];
    __shared__ float P[64][65];
    __shared__ float Ms[64];
    __shared__ float Rl[64];
    int bh = blockIdx.y;
    int b = bh >> 3, h = bh & 7;
    int t0 = blockIdx.x * 64;
    int tid = threadIdx.x, tx = tid & 15, ty = tid >> 4;

    // Load Q tile once
#pragma unroll
    for (int p = 0; p < 2; ++p) {
        int i4 = tid + p * 256;
        int tl = i4 >> 3;
        int dq = i4 & 7;
        const float4 v4 = *(const float4*)&qkv[((size_t)(b * TT + t0 + tl) * 768) + h * TD + dq * 4];
        Qs[dq * 4 + 0][tl] = v4.x;
        Qs[dq * 4 + 1][tl] = v4.y;
        Qs[dq * 4 + 2][tl] = v4.z;
        Qs[dq * 4 + 3][tl] = v4.w;
    }

    int row0 = tid >> 3;        // 0..31
    int row1 = row0 + 32;       // 32..63
    int dg = tid & 7;           // 0..7 (x4 d's)
    float4 acc0 = make_float4(0.f, 0.f, 0.f, 0.f);
    float4 acc1 = make_float4(0.f, 0.f, 0.f, 0.f);

    for (int s0 = 0; s0 <= t0; s0 += 64) {
        __syncthreads();   // prev phase B done; Qs ready on first iter
        // Load K (transposed), V tiles and column stats
#pragma unroll
        for (int p = 0; p < 2; ++p) {
            int i4 = tid + p * 256;
            int sl = i4 >> 3;
            int dq = i4 & 7;
            size_t base = ((size_t)(b * TT + s0 + sl) * 768) + h * TD + dq * 4;
            const float4 kv = *(const float4*)&qkv[base + 256];
            Ks[dq * 4 + 0][sl] = kv.x;
            Ks[dq * 4 + 1][sl] = kv.y;
            Ks[dq * 4 + 2][sl] = kv.z;
            Ks[dq * 4 + 3][sl] = kv.w;
            const float4 vv = *(const float4*)&qkv[base + 512];
            *(float4*)&Vs[sl][dq * 4] = vv;
        }
        if (tid < 64) {
            Ms[tid] = colM[(size_t)bh * TT + s0 + tid];
            Rl[tid] = 1.0f / colL[(size_t)bh * TT + s0 + tid];
        }
        __syncthreads();

        // Phase A: P tile
        float sc[4][4] = {};
#pragma unroll
        for (int d = 0; d < TD; ++d) {
            float4 a4 = *(const float4*)&Qs[d][ty * 4];
            float4 b4 = *(const float4*)&Ks[d][tx * 4];
            float av[4] = {a4.x, a4.y, a4.z, a4.w};
            float bv[4] = {b4.x, b4.y, b4.z, b4.w};
#pragma unroll
            for (int i = 0; i < 4; ++i)
#pragma unroll
                for (int j = 0; j < 4; ++j)
                    sc[i][j] = fmaf(av[i], bv[j], sc[i][j]);
        }
        bool edge = (s0 == t0);
#pragma unroll
        for (int j = 0; j < 4; ++j) {
            int sl = tx * 4 + j;
            float Mv = Ms[sl], R = Rl[sl];
#pragma unroll
            for (int i = 0; i < 4; ++i) {
                int tl = ty * 4 + i;
                float pv = __expf(sc[i][j] * SCALE - Mv) * R;
                if (edge && tl < sl) pv = 0.f;   // causal: s <= t
                P[tl][sl] = pv;
            }
        }
        __syncthreads();

        // Phase B: O += P @ V
#pragma unroll 8
        for (int sl = 0; sl < 64; ++sl) {
            float p0 = P[row0][sl];
            float p1 = P[row1][sl];
            float4 v4 = *(const float4*)&Vs[sl][dg * 4];
            acc0.x = fmaf(p0, v4.x, acc0.x);
            acc0.y = fmaf(p0, v4.y, acc0.y);
            acc0.z = fmaf(p0, v4.z, acc0.z);
            acc0.w = fmaf(p0, v4.w, acc0.w);
            acc1.x = fmaf(p1, v4.x, acc1.x);
            acc1.y = fmaf(p1, v4.y, acc1.y);
            acc1.z = fmaf(p1, v4.z, acc1.z);
            acc1.w = fmaf(p1, v4.w, acc1.w);
        }
    }

    // Epilogue: xh = xn + heads
    size_t base0 = ((size_t)(b * TT) + t0 + row0) * TE + h * TD + dg * 4;
    size_t base1 = ((size_t)(b * TT) + t0 + row1) * TE + h * TD + dg * 4;
    float4 x0 = *(const float4*)&xn[base0];
    float4 x1 = *(const float4*)&xn[base1];
    x0.x += acc0.x; x0.y += acc0.y; x0.z += acc0.z; x0.w += acc0.w;
    x1.x += acc1.x; x1.y += acc1.y; x1.z += acc1.z; x1.w += acc1.w;
    *(float4*)&xh[base0] = x0;
    *(float4*)&xh[base1] = x1;
}

// ---------------------------------------------------------------------------
extern "C" void kernel_launch(void* const* d_in, const int* in_sizes, int n_in,
                              void* d_out, int out_size, void* d_ws, size_t ws_size,
                              hipStream_t stream) {
    (void)in_sizes; (void)n_in; (void)out_size; (void)ws_size;
    const float* x      = (const float*)d_in[0];
    const float* wq     = (const float*)d_in[1];
    const float* wk     = (const float*)d_in[2];
    const float* wv     = (const float*)d_in[3];
    const float* w_lin  = (const float*)d_in[4];
    const float* b_lin  = (const float*)d_in[5];
    const float* g1     = (const float*)d_in[6];
    const float* beta1  = (const float*)d_in[7];
    const float* g2     = (const float*)d_in[8];
    const float* beta2  = (const float*)d_in[9];
    const float* w_f1   = (const float*)d_in[10];
    const float* b_f1   = (const float*)d_in[11];
    const float* w_f2   = (const float*)d_in[12];
    const float* b_f2   = (const float*)d_in[13];
    float* out = (float*)d_out;

    // Workspace layout (floats), with aliasing:
    //   region0: xn (later xl)                      4,194,304
    //   region1: qkv|wpack|colM|colL|xh  (later hidden) 17,235,968
    //   region2: x2                                 4,194,304
    float* ws = (float*)d_ws;
    float* xn     = ws;                       // 4,194,304
    float* region1 = ws + 4194304;
    float* qkvb   = region1;                  // 12,582,912
    float* wpack  = region1 + 12582912;       //    196,608
    float* cM     = wpack + 196608;           //    131,072
    float* cL     = cM + 131072;              //    131,072
    float* xh     = cL + 131072;              //  4,194,304 (region1 end: 17,235,968)
    float* hidden = region1;                  // 16,777,216 (aliases dead qkv/wpack/cM/cL/xh区)
    float* x2     = region1 + 17235968;       //  4,194,304
    float* xl     = xn;                       // aliases xn (dead after pass2)

    pack_w_k<<<768, 256, 0, stream>>>(wq, wk, wv, wpack);
    ln_k<<<NTOK, 256, 0, stream>>>(x, g1, beta1, xn);
    gemm_k<<<dim3(768 / BN, NTOK / BM), 256, 0, stream>>>(xn, wpack, nullptr, nullptr, qkvb,
                                                          NTOK, 768, TE, 0);
    attn_pass1<<<dim3(TT / 64, TB * TH), 256, 0, stream>>>(qkvb, cM, cL);
    attn_pass2<<<dim3(TT / 64, TB * TH), 256, 0, stream>>>(qkvb, cM, cL, xn, xh);
    gemm_k<<<dim3(TE / BN, NTOK / BM), 256, 0, stream>>>(xh, w_lin, b_lin, nullptr, xl,
                                                         NTOK, TE, TE, 0);
    ln_k<<<NTOK, 256, 0, stream>>>(xl, g2, beta2, x2);
    gemm_k<<<dim3(TF / BN, NTOK / BM), 256, 0, stream>>>(x2, w_f1, b_f1, nullptr, hidden,
                                                         NTOK, TF, TE, 1);
    gemm_k<<<dim3(TE / BN, NTOK / BM), 256, 0, stream>>>(hidden, w_f2, b_f2, x2, out,
                                                         NTOK, TE, TF, 0);
}

// Round 2
// 524.202 us; speedup vs baseline: 3.6198x; 3.6198x over previous
//
#include <hip/hip_runtime.h>
#include <math.h>

// B=8, T=2048, E=256, H=8, D=32, F=1024
#define TT 2048
#define TE 256
#define SCALE 0.0625f   // 256^-0.5, baked into Q at bf16-convert time

typedef short  bf16x8 __attribute__((ext_vector_type(8)));
typedef float  f32x4  __attribute__((ext_vector_type(4)));
typedef unsigned short u16x8 __attribute__((ext_vector_type(8)));

__device__ __forceinline__ unsigned short f2b(float f) {
    union { float f; unsigned int u; } v; v.f = f;
    unsigned int r = v.u + 0x7FFF + ((v.u >> 16) & 1);   // RNE
    return (unsigned short)(r >> 16);
}
__device__ __forceinline__ bf16x8 ld8(const unsigned short* p) {
    return *(const bf16x8*)p;
}
#define MFMA(a, b, c) __builtin_amdgcn_mfma_f32_16x16x32_bf16((a), (b), (c), 0, 0, 0)

// ---------------------------------------------------------------------------
// Weight convert/transpose to bf16 [N][K] row-major (b_frag wants contiguous k)
__global__ __launch_bounds__(256) void conv_w(const float* __restrict__ wq,
                                              const float* __restrict__ wk,
                                              const float* __restrict__ wv,
                                              const float* __restrict__ w_lin,
                                              const float* __restrict__ w_f1,
                                              const float* __restrict__ w_f2,
                                              unsigned short* __restrict__ Wqkv,
                                              unsigned short* __restrict__ Wlin,
                                              unsigned short* __restrict__ Wf1,
                                              unsigned short* __restrict__ Wf2) {
    int idx = blockIdx.x * 256 + threadIdx.x;
    if (idx < 196608) {                       // Wqkv_t [768][256]
        int n = idx >> 8, k = idx & 255;
        int which = n >> 8, h = (n >> 5) & 7, d = n & 31;
        const float* w = (which == 0) ? wq : (which == 1) ? wk : wv;
        Wqkv[idx] = f2b(w[(h * 256 + k) * 32 + d]);
    } else if (idx < 262144) {                // Wlin_t [256][256]
        int i = idx - 196608; int n = i >> 8, k = i & 255;
        Wlin[i] = f2b(w_lin[k * 256 + n]);
    } else if (idx < 524288) {                // Wf1_t [1024][256]
        int i = idx - 262144; int n = i >> 8, k = i & 255;
        Wf1[i] = f2b(w_f1[k * 1024 + n]);
    } else {                                  // Wf2_t [256][1024]
        int i = idx - 524288; int n = i >> 10, k = i & 1023;
        Wf2[i] = f2b(w_f2[k * 256 + n]);
    }
}

// ---------------------------------------------------------------------------
// LayerNorm over E=256, one block/row, fp32 + optional bf16 outputs
__global__ __launch_bounds__(256) void ln_dual(const float* __restrict__ X,
                                               const float* __restrict__ g,
                                               const float* __restrict__ bta,
                                               float* __restrict__ Y,
                                               unsigned short* __restrict__ Yb) {
    __shared__ float s1[256];
    __shared__ float s2[256];
    int row = blockIdx.x, t = threadIdx.x;
    float v = X[(size_t)row * TE + t];
    s1[t] = v; s2[t] = v * v;
    __syncthreads();
    for (int s = 128; s > 0; s >>= 1) {
        if (t < s) { s1[t] += s1[t + s]; s2[t] += s2[t + s]; }
        __syncthreads();
    }
    float mean = s1[0] * (1.0f / TE);
    float var = s2[0] * (1.0f / TE) - mean * mean;
    float rstd = rsqrtf(var + 1e-5f);
    float o = (v - mean) * rstd * g[t] + bta[t];
    if (Y)  Y[(size_t)row * TE + t] = o;
    if (Yb) Yb[(size_t)row * TE + t] = f2b(o);
}

// ---------------------------------------------------------------------------
// Generic bf16 MFMA GEMM: C[M,N] = A[M,K] @ Wt[N,K]^T, no LDS, 4 waves x 16 rows.
__global__ __launch_bounds__(256) void gemm_bf16(const unsigned short* __restrict__ A,
                                                 const unsigned short* __restrict__ Bt,
                                                 const float* __restrict__ bias,
                                                 const float* __restrict__ resid,
                                                 float* __restrict__ outF,
                                                 unsigned short* __restrict__ outB,
                                                 int N, int K, int relu) {
    int tid = threadIdx.x;
    int w = tid >> 6, lane = tid & 63, q = lane >> 4, col = lane & 15;
    int m0 = blockIdx.y * 64 + w * 16;
    int n0 = blockIdx.x * 64;
    f32x4 acc[4] = {{0,0,0,0},{0,0,0,0},{0,0,0,0},{0,0,0,0}};
    const unsigned short* ar = A + (size_t)(m0 + col) * K + q * 8;
    const unsigned short* b0 = Bt + (size_t)(n0 + col) * K + q * 8;
    const unsigned short* b1 = b0 + (size_t)16 * K;
    const unsigned short* b2 = b0 + (size_t)32 * K;
    const unsigned short* b3 = b0 + (size_t)48 * K;
#pragma unroll 4
    for (int k0 = 0; k0 < K; k0 += 32) {
        bf16x8 a = ld8(ar + k0);
        acc[0] = MFMA(a, ld8(b0 + k0), acc[0]);
        acc[1] = MFMA(a, ld8(b1 + k0), acc[1]);
        acc[2] = MFMA(a, ld8(b2 + k0), acc[2]);
        acc[3] = MFMA(a, ld8(b3 + k0), acc[3]);
    }
#pragma unroll
    for (int j = 0; j < 4; ++j) {
        int n = n0 + j * 16 + col;
#pragma unroll
        for (int r = 0; r < 4; ++r) {
            int m = m0 + q * 4 + r;
            float v = acc[j][r];
            if (bias) v += bias[n];
            if (relu) v = fmaxf(v, 0.f);
            if (resid) v += resid[(size_t)m * N + n];
            if (outF) outF[(size_t)m * N + n] = v;
            if (outB) outB[(size_t)m * N + n] = f2b(v);
        }
    }
}

// ---------------------------------------------------------------------------
// QKV GEMM: A=xn_bf (16384x256) @ Wqkv_t(768x256)^T; scatter epilogue into
// Qbf (x1/16, bf16), Kbf (bf16), Vf (fp32), all laid out [bh][t][32].
__global__ __launch_bounds__(256) void gemm_qkv(const unsigned short* __restrict__ A,
                                                const unsigned short* __restrict__ Bt,
                                                unsigned short* __restrict__ Qbf,
                                                unsigned short* __restrict__ Kbf,
                                                float* __restrict__ Vf) {
    const int K = 256;
    int tid = threadIdx.x;
    int w = tid >> 6, lane = tid & 63, q = lane >> 4, col = lane & 15;
    int m0 = blockIdx.y * 64 + w * 16;
    int n0 = blockIdx.x * 64;
    f32x4 acc[4] = {{0,0,0,0},{0,0,0,0},{0,0,0,0},{0,0,0,0}};
    const unsigned short* ar = A + (size_t)(m0 + col) * K + q * 8;
    const unsigned short* b0 = Bt + (size_t)(n0 + col) * K + q * 8;
#pragma unroll
    for (int k0 = 0; k0 < K; k0 += 32) {
        bf16x8 a = ld8(ar + k0);
        acc[0] = MFMA(a, ld8(b0 + k0), acc[0]);
        acc[1] = MFMA(a, ld8(b0 + 16 * K + k0), acc[1]);
        acc[2] = MFMA(a, ld8(b0 + 32 * K + k0), acc[2]);
        acc[3] = MFMA(a, ld8(b0 + 48 * K + k0), acc[3]);
    }
#pragma unroll
    for (int j = 0; j < 4; ++j) {
        int n = n0 + j * 16 + col;
        int which = n >> 8, h = (n >> 5) & 7, d = n & 31;
#pragma unroll
        for (int r = 0; r < 4; ++r) {
            int m = m0 + q * 4 + r;
            int b = m >> 11, t = m & 2047;
            size_t idx = ((size_t)(b * 8 + h) * TT + t) * 32 + d;
            float v = acc[j][r];
            if (which == 0)      Qbf[idx] = f2b(v * SCALE);
            else if (which == 1) Kbf[idx] = f2b(v);
            else                 Vf[idx]  = v;
        }
    }
}

// ---------------------------------------------------------------------------
// Pass 1: column sums L_s = sum_{t>=s} exp(q_t . k_s) (scale baked into Q).
// Block = 4 waves x 16 columns; each wave holds its K-frag in regs, streams Q.
__global__ __launch_bounds__(256) void attn_cols(const unsigned short* __restrict__ Qbf,
                                                 const unsigned short* __restrict__ Kbf,
                                                 float* __restrict__ colL) {
    int tid = threadIdx.x;
    int w = tid >> 6, lane = tid & 63, q = lane >> 4, col = lane & 15;
    int bh = blockIdx.y;
    int sbase = blockIdx.x * 64 + w * 16;
    const unsigned short* Qb = Qbf + (size_t)bh * TT * 32;
    bf16x8 kf = ld8(&Kbf[((size_t)bh * TT + sbase + col) * 32 + q * 8]);
    f32x4 z = {0, 0, 0, 0};
    float acc = 0.f;
    {   // diagonal tile: mask t_local >= s_local
        bf16x8 a = ld8(&Qb[(size_t)(sbase + col) * 32 + q * 8]);
        f32x4 sc = MFMA(a, kf, z);
#pragma unroll
        for (int r = 0; r < 4; ++r)
            if (q * 4 + r >= col) acc += __expf(sc[r]);
    }
#pragma unroll 2
    for (int t0 = sbase + 16; t0 < TT; t0 += 16) {
        bf16x8 a = ld8(&Qb[(size_t)(t0 + col) * 32 + q * 8]);
        f32x4 sc = MFMA(a, kf, z);
#pragma unroll
        for (int r = 0; r < 4; ++r) acc += __expf(sc[r]);
    }
    acc += __shfl_xor(acc, 16, 64);
    acc += __shfl_xor(acc, 32, 64);
    if (lane < 16) colL[(size_t)bh * TT + sbase + lane] = acc;
}

// ---------------------------------------------------------------------------
// Scale+transpose V: Vt[bh][d][s] = Vf[bh][s][d] / L_s   (bf16)
__global__ __launch_bounds__(256) void scale_v(const float* __restrict__ Vf,
                                               const float* __restrict__ colL,
                                               unsigned short* __restrict__ Vt) {
    __shared__ float tile[64][33];
    int bh = blockIdx.y, s0 = blockIdx.x * 64, tid = threadIdx.x;
    int r = tid >> 2, c4 = (tid & 3) * 8;
    float rl = 1.0f / colL[(size_t)bh * TT + s0 + r];
    const float* src = &Vf[((size_t)bh * TT + s0 + r) * 32 + c4];
    float4 v0 = *(const float4*)src;
    float4 v1 = *(const float4*)(src + 4);
    tile[r][c4 + 0] = v0.x * rl; tile[r][c4 + 1] = v0.y * rl;
    tile[r][c4 + 2] = v0.z * rl; tile[r][c4 + 3] = v0.w * rl;
    tile[r][c4 + 4] = v1.x * rl; tile[r][c4 + 5] = v1.y * rl;
    tile[r][c4 + 6] = v1.z * rl; tile[r][c4 + 7] = v1.w * rl;
    __syncthreads();
    int d = tid >> 3, sl = (tid & 7) * 8;
    u16x8 o;
#pragma unroll
    for (int i = 0; i < 8; ++i) o[i] = f2b(tile[sl + i][d]);
    *(u16x8*)&Vt[((size_t)bh * 32 + d) * TT + s0 + sl] = o;
}

// ---------------------------------------------------------------------------
// Pass 2: O[t,:] = sum_{s<=t} exp(q_t.k_s) * V'[s,:]; epilogue xh_bf = bf16(xn + O).
// Block = 64 t rows (4 waves x 16); loop 64-s chunks staged in LDS.
__global__ __launch_bounds__(256) void attn_out(const unsigned short* __restrict__ Qbf,
                                                const unsigned short* __restrict__ Kbf,
                                                const unsigned short* __restrict__ Vt,
                                                const float* __restrict__ xn,
                                                unsigned short* __restrict__ xh_bf) {
    __shared__ unsigned short Ks[64][72];
    __shared__ unsigned short Vts[32][72];
    __shared__ unsigned short Pw[4][16][72];
    int tid = threadIdx.x;
    int w = tid >> 6, lane = tid & 63, q = lane >> 4, col = lane & 15;
    int bh = blockIdx.y;
    int t0 = blockIdx.x * 64;
    int twave = t0 + w * 16;
    f32x4 z = {0, 0, 0, 0};
    bf16x8 qf = ld8(&Qbf[((size_t)bh * TT + twave + col) * 32 + q * 8]);
    f32x4 acc0 = z, acc1 = z;
    int nchunk = blockIdx.x + 1;
    int kr = tid >> 2, kp = tid & 3;      // K staging: 64 rows x 4 parts
    int vd = tid >> 3, vp = tid & 7;      // V staging: 32 d x 8 parts
    for (int c = 0; c < nchunk; ++c) {
        int s0 = c * 64;
        __syncthreads();
        *(uint4*)&Ks[kr][kp * 8] =
            *(const uint4*)&Kbf[((size_t)bh * TT + s0 + kr) * 32 + kp * 8];
        *(uint4*)&Vts[vd][vp * 8] =
            *(const uint4*)&Vt[((size_t)bh * 32 + vd) * TT + s0 + vp * 8];
        __syncthreads();
        if (s0 > twave + 15) continue;    // this wave done (still hits barriers)
#pragma unroll
        for (int sub = 0; sub < 4; ++sub) {
            int ssub = s0 + sub * 16;
            f32x4 sc = z;
            if (ssub <= twave + 15) {
                bf16x8 kb = ld8(&Ks[sub * 16 + col][q * 8]);
                sc = MFMA(qf, kb, z);
            }
            int s_g = ssub + col;
#pragma unroll
            for (int r = 0; r < 4; ++r) {
                int t_g = twave + q * 4 + r;
                float p = (s_g <= t_g) ? __expf(sc[r]) : 0.f;
                Pw[w][q * 4 + r][sub * 16 + col] = f2b(p);
            }
        }
#pragma unroll
        for (int kc = 0; kc < 2; ++kc) {
            bf16x8 pa = ld8(&Pw[w][col][kc * 32 + q * 8]);
            bf16x8 v0 = ld8(&Vts[col][kc * 32 + q * 8]);
            bf16x8 v1 = ld8(&Vts[16 + col][kc * 32 + q * 8]);
            acc0 = MFMA(pa, v0, acc0);
            acc1 = MFMA(pa, v1, acc1);
        }
    }
    int b = bh >> 3, h = bh & 7;
#pragma unroll
    for (int r = 0; r < 4; ++r) {
        int t_g = twave + q * 4 + r;
        size_t base = ((size_t)(b * TT + t_g)) * TE + h * 32;
        xh_bf[base + col]      = f2b(acc0[r] + xn[base + col]);
        xh_bf[base + 16 + col] = f2b(acc1[r] + xn[base + 16 + col]);
    }
}

// ---------------------------------------------------------------------------
extern "C" void kernel_launch(void* const* d_in, const int* in_sizes, int n_in,
                              void* d_out, int out_size, void* d_ws, size_t ws_size,
                              hipStream_t stream) {
    (void)in_sizes; (void)n_in; (void)out_size; (void)ws_size;
    const float* x     = (const float*)d_in[0];
    const float* wq    = (const float*)d_in[1];
    const float* wk    = (const float*)d_in[2];
    const float* wv    = (const float*)d_in[3];
    const float* w_lin = (const float*)d_in[4];
    const float* b_lin = (const float*)d_in[5];
    const float* g1    = (const float*)d_in[6];
    const float* beta1 = (const float*)d_in[7];
    const float* g2    = (const float*)d_in[8];
    const float* beta2 = (const float*)d_in[9];
    const float* w_f1  = (const float*)d_in[10];
    const float* b_f1  = (const float*)d_in[11];
    const float* w_f2  = (const float*)d_in[12];
    const float* b_f2  = (const float*)d_in[13];
    float* out = (float*)d_out;

    // Byte-offset workspace layout (74 MB; aliases noted)
    char* ws = (char*)d_ws;
    unsigned short* Wqkv_t = (unsigned short*)(ws + 0);         //  384 KB
    unsigned short* Wlin_t = (unsigned short*)(ws + 393216);    //  128 KB
    unsigned short* Wf1_t  = (unsigned short*)(ws + 524288);    //  512 KB
    unsigned short* Wf2_t  = (unsigned short*)(ws + 1048576);   //  512 KB
    float*          xn     = (float*)(ws + 1572864);            //   16 MB  [xl aliases]
    unsigned short* xn_bf  = (unsigned short*)(ws + 18350080);  //    8 MB  [x2_bf aliases]
    unsigned short* Qbf    = (unsigned short*)(ws + 26738688);  //    8 MB ┐
    unsigned short* Kbf    = (unsigned short*)(ws + 35127296);  //    8 MB ├ h_bf aliases (32 MB)
    unsigned short* Vt     = (unsigned short*)(ws + 43515904);  //    8 MB │
    unsigned short* xh_bf  = (unsigned short*)(ws + 51904512);  //    8 MB ┘
    float*          Vf     = (float*)(ws + 60293120);           //   16 MB  [x2 aliases]
    float*          colL   = (float*)(ws + 77070336);           //  512 KB
    float*          xl     = xn;
    unsigned short* x2_bf  = xn_bf;
    unsigned short* h_bf   = Qbf;
    float*          x2     = Vf;

    conv_w<<<3072, 256, 0, stream>>>(wq, wk, wv, w_lin, w_f1, w_f2,
                                     Wqkv_t, Wlin_t, Wf1_t, Wf2_t);
    ln_dual<<<16384, 256, 0, stream>>>(x, g1, beta1, xn, xn_bf);
    gemm_qkv<<<dim3(12, 256), 256, 0, stream>>>(xn_bf, Wqkv_t, Qbf, Kbf, Vf);
    attn_cols<<<dim3(32, 64), 256, 0, stream>>>(Qbf, Kbf, colL);
    scale_v<<<dim3(32, 64), 256, 0, stream>>>(Vf, colL, Vt);
    attn_out<<<dim3(32, 64), 256, 0, stream>>>(Qbf, Kbf, Vt, xn, xh_bf);
    gemm_bf16<<<dim3(4, 256), 256, 0, stream>>>(xh_bf, Wlin_t, b_lin, nullptr,
                                                xl, nullptr, 256, 256, 0);
    ln_dual<<<16384, 256, 0, stream>>>(xl, g2, beta2, x2, x2_bf);
    gemm_bf16<<<dim3(16, 256), 256, 0, stream>>>(x2_bf, Wf1_t, b_f1, nullptr,
                                                 nullptr, h_bf, 1024, 256, 1);
    gemm_bf16<<<dim3(4, 256), 256, 0, stream>>>(h_bf, Wf2_t, b_f2, x2,
                                                out, nullptr, 256, 1024, 0);
}

// Round 3
// 468.871 us; speedup vs baseline: 4.0470x; 1.1180x over previous
//
#include <hip/hip_runtime.h>
#include <math.h>

// B=8, T=2048, E=256, H=8, D=32, F=1024
#define TT 2048
#define TE 256
// Q pre-scale: 256^-0.5 * log2(e)  (so softmax exp == exp2 of scores)
#define QSCALE (0.0625f * 1.44269504088896f)

typedef short  bf16x8 __attribute__((ext_vector_type(8)));
typedef float  f32x4  __attribute__((ext_vector_type(4)));
typedef float  f32x16 __attribute__((ext_vector_type(16)));
typedef unsigned short u16x4 __attribute__((ext_vector_type(4)));
typedef unsigned short u16x8 __attribute__((ext_vector_type(8)));

__device__ __forceinline__ unsigned short f2b(float f) {
    union { float f; unsigned int u; } v; v.f = f;
    unsigned int r = v.u + 0x7FFF + ((v.u >> 16) & 1);   // RNE
    return (unsigned short)(r >> 16);
}
__device__ __forceinline__ unsigned int pk_bf16(float a, float b) {
#if defined(__has_builtin) && __has_builtin(__builtin_amdgcn_cvt_pk_bf16_f32)
    typedef __bf16 bf2 __attribute__((ext_vector_type(2)));
    union { bf2 v; unsigned int u; } u;
    u.v = __builtin_amdgcn_cvt_pk_bf16_f32(a, b);
    return u.u;
#else
    return (unsigned int)f2b(a) | ((unsigned int)f2b(b) << 16);
#endif
}
__device__ __forceinline__ bf16x8 ld8(const unsigned short* p) {
    return *(const bf16x8*)p;
}
#define MFMA16(a, b, c) __builtin_amdgcn_mfma_f32_16x16x32_bf16((a), (b), (c), 0, 0, 0)
#define MFMA32(a, b, c) __builtin_amdgcn_mfma_f32_32x32x16_bf16((a), (b), (c), 0, 0, 0)

// ---------------------------------------------------------------------------
// Weight convert/transpose to bf16 [N][K] row-major
__global__ __launch_bounds__(256) void conv_w(const float* __restrict__ wq,
                                              const float* __restrict__ wk,
                                              const float* __restrict__ wv,
                                              const float* __restrict__ w_lin,
                                              const float* __restrict__ w_f1,
                                              const float* __restrict__ w_f2,
                                              unsigned short* __restrict__ Wqkv,
                                              unsigned short* __restrict__ Wlin,
                                              unsigned short* __restrict__ Wf1,
                                              unsigned short* __restrict__ Wf2) {
    int idx = blockIdx.x * 256 + threadIdx.x;
    if (idx < 196608) {                       // Wqkv_t [768][256]
        int n = idx >> 8, k = idx & 255;
        int which = n >> 8, h = (n >> 5) & 7, d = n & 31;
        const float* w = (which == 0) ? wq : (which == 1) ? wk : wv;
        Wqkv[idx] = f2b(w[(h * 256 + k) * 32 + d]);
    } else if (idx < 262144) {                // Wlin_t [256][256]
        int i = idx - 196608; int n = i >> 8, k = i & 255;
        Wlin[i] = f2b(w_lin[k * 256 + n]);
    } else if (idx < 524288) {                // Wf1_t [1024][256]
        int i = idx - 262144; int n = i >> 8, k = i & 255;
        Wf1[i] = f2b(w_f1[k * 1024 + n]);
    } else {                                  // Wf2_t [256][1024]
        int i = idx - 524288; int n = i >> 10, k = i & 1023;
        Wf2[i] = f2b(w_f2[k * 256 + n]);
    }
}

// ---------------------------------------------------------------------------
// LayerNorm, wave-per-row (E=256 = 64 lanes x float4), shuffle reduce, no LDS
__global__ __launch_bounds__(256) void ln_w(const float* __restrict__ X,
                                            const float* __restrict__ g,
                                            const float* __restrict__ bta,
                                            float* __restrict__ Y,
                                            unsigned short* __restrict__ Yb) {
    int row = blockIdx.x * 4 + (threadIdx.x >> 6);
    int lane = threadIdx.x & 63;
    const float4 v = *(const float4*)&X[(size_t)row * TE + lane * 4];
    float s = v.x + v.y + v.z + v.w;
    float s2 = v.x * v.x + v.y * v.y + v.z * v.z + v.w * v.w;
#pragma unroll
    for (int off = 1; off <= 32; off <<= 1) {
        s  += __shfl_xor(s,  off, 64);
        s2 += __shfl_xor(s2, off, 64);
    }
    float mean = s * (1.0f / TE);
    float var = s2 * (1.0f / TE) - mean * mean;
    float rstd = rsqrtf(var + 1e-5f);
    const float4 gg = *(const float4*)&g[lane * 4];
    const float4 bb = *(const float4*)&bta[lane * 4];
    float4 o;
    o.x = (v.x - mean) * rstd * gg.x + bb.x;
    o.y = (v.y - mean) * rstd * gg.y + bb.y;
    o.z = (v.z - mean) * rstd * gg.z + bb.z;
    o.w = (v.w - mean) * rstd * gg.w + bb.w;
    if (Y) *(float4*)&Y[(size_t)row * TE + lane * 4] = o;
    if (Yb) {
        u16x4 ob = { f2b(o.x), f2b(o.y), f2b(o.z), f2b(o.w) };
        *(u16x4*)&Yb[(size_t)row * TE + lane * 4] = ob;
    }
}

// ---------------------------------------------------------------------------
// bf16 MFMA GEMM: C[M,N] = A[M,K] @ Wt[N,K]^T. 4 waves x 32 m-rows, 64 n.
__global__ __launch_bounds__(256) void gemm_bf16(const unsigned short* __restrict__ A,
                                                 const unsigned short* __restrict__ Bt,
                                                 const float* __restrict__ bias,
                                                 const float* __restrict__ resid,
                                                 float* __restrict__ outF,
                                                 unsigned short* __restrict__ outB,
                                                 int N, int K, int relu) {
    int tid = threadIdx.x;
    int w = tid >> 6, lane = tid & 63, q = lane >> 4, col = lane & 15;
    int m0 = blockIdx.y * 128 + w * 32;
    int n0 = blockIdx.x * 64;
    f32x4 acc[2][4] = {};
    const unsigned short* ar0 = A + (size_t)(m0 + col) * K + q * 8;
    const unsigned short* ar1 = ar0 + (size_t)16 * K;
    const unsigned short* bp0 = Bt + (size_t)(n0 + col) * K + q * 8;
    const unsigned short* bp1 = bp0 + (size_t)16 * K;
    const unsigned short* bp2 = bp0 + (size_t)32 * K;
    const unsigned short* bp3 = bp0 + (size_t)48 * K;
#pragma unroll 4
    for (int k0 = 0; k0 < K; k0 += 32) {
        bf16x8 a0 = ld8(ar0 + k0);
        bf16x8 a1 = ld8(ar1 + k0);
        bf16x8 b0 = ld8(bp0 + k0), b1 = ld8(bp1 + k0);
        bf16x8 b2 = ld8(bp2 + k0), b3 = ld8(bp3 + k0);
        acc[0][0] = MFMA16(a0, b0, acc[0][0]); acc[1][0] = MFMA16(a1, b0, acc[1][0]);
        acc[0][1] = MFMA16(a0, b1, acc[0][1]); acc[1][1] = MFMA16(a1, b1, acc[1][1]);
        acc[0][2] = MFMA16(a0, b2, acc[0][2]); acc[1][2] = MFMA16(a1, b2, acc[1][2]);
        acc[0][3] = MFMA16(a0, b3, acc[0][3]); acc[1][3] = MFMA16(a1, b3, acc[1][3]);
    }
#pragma unroll
    for (int i = 0; i < 2; ++i)
#pragma unroll
    for (int j = 0; j < 4; ++j) {
        int n = n0 + j * 16 + col;
#pragma unroll
        for (int r = 0; r < 4; ++r) {
            int m = m0 + i * 16 + q * 4 + r;
            float v = acc[i][j][r];
            if (bias) v += bias[n];
            if (relu) v = fmaxf(v, 0.f);
            if (resid) v += resid[(size_t)m * N + n];
            if (outF) outF[(size_t)m * N + n] = v;
            if (outB) outB[(size_t)m * N + n] = f2b(v);
        }
    }
}

// ---------------------------------------------------------------------------
// QKV GEMM, scatter epilogue: Qbf (x QSCALE), Kbf, Vf; layout [bh][t][32]
__global__ __launch_bounds__(256) void gemm_qkv(const unsigned short* __restrict__ A,
                                                const unsigned short* __restrict__ Bt,
                                                unsigned short* __restrict__ Qbf,
                                                unsigned short* __restrict__ Kbf,
                                                float* __restrict__ Vf) {
    const int K = 256;
    int tid = threadIdx.x;
    int w = tid >> 6, lane = tid & 63, q = lane >> 4, col = lane & 15;
    int m0 = blockIdx.y * 128 + w * 32;
    int n0 = blockIdx.x * 64;
    f32x4 acc[2][4] = {};
    const unsigned short* ar0 = A + (size_t)(m0 + col) * K + q * 8;
    const unsigned short* ar1 = ar0 + (size_t)16 * K;
    const unsigned short* bp0 = Bt + (size_t)(n0 + col) * K + q * 8;
#pragma unroll
    for (int k0 = 0; k0 < K; k0 += 32) {
        bf16x8 a0 = ld8(ar0 + k0);
        bf16x8 a1 = ld8(ar1 + k0);
        bf16x8 b0 = ld8(bp0 + k0), b1 = ld8(bp0 + 16 * K + k0);
        bf16x8 b2 = ld8(bp0 + 32 * K + k0), b3 = ld8(bp0 + 48 * K + k0);
        acc[0][0] = MFMA16(a0, b0, acc[0][0]); acc[1][0] = MFMA16(a1, b0, acc[1][0]);
        acc[0][1] = MFMA16(a0, b1, acc[0][1]); acc[1][1] = MFMA16(a1, b1, acc[1][1]);
        acc[0][2] = MFMA16(a0, b2, acc[0][2]); acc[1][2] = MFMA16(a1, b2, acc[1][2]);
        acc[0][3] = MFMA16(a0, b3, acc[0][3]); acc[1][3] = MFMA16(a1, b3, acc[1][3]);
    }
#pragma unroll
    for (int i = 0; i < 2; ++i)
#pragma unroll
    for (int j = 0; j < 4; ++j) {
        int n = n0 + j * 16 + col;
        int which = n >> 8, h = (n >> 5) & 7, d = n & 31;
#pragma unroll
        for (int r = 0; r < 4; ++r) {
            int m = m0 + i * 16 + q * 4 + r;
            int b = m >> 11, t = m & 2047;
            size_t idx = ((size_t)(b * 8 + h) * TT + t) * 32 + d;
            float v = acc[i][j][r];
            if (which == 0)      Qbf[idx] = f2b(v * QSCALE);
            else if (which == 1) Kbf[idx] = f2b(v);
            else                 Vf[idx]  = v;
        }
    }
}

// ---------------------------------------------------------------------------
// Pass 1: colL[s] = sum_{t>=s} exp2(q_t . k_s). Wave owns 32 s (K resident in
// regs, 32x32x16 MFMA), streams Q in 32-t steps. No LDS, no barriers.
__global__ __launch_bounds__(256) void attn_cols(const unsigned short* __restrict__ Qbf,
                                                 const unsigned short* __restrict__ Kbf,
                                                 float* __restrict__ colL) {
    int tid = threadIdx.x;
    int w = tid >> 6, lane = tid & 63, hi = lane >> 5, l31 = lane & 31;
    int bh = blockIdx.y;
    int sbase = blockIdx.x * 128 + w * 32;
    const unsigned short* Qb = Qbf + (size_t)bh * TT * 32;
    const unsigned short* Kb = Kbf + (size_t)bh * TT * 32;
    bf16x8 a0 = ld8(Kb + (size_t)(sbase + l31) * 32 + hi * 8);        // d 0..15
    bf16x8 a1 = ld8(Kb + (size_t)(sbase + l31) * 32 + 16 + hi * 8);   // d 16..31
    const f32x16 z16 = {};
    float acc[16] = {};
    for (int t0 = sbase; t0 < TT; t0 += 32) {
        bf16x8 q0 = ld8(Qb + (size_t)(t0 + l31) * 32 + hi * 8);
        bf16x8 q1 = ld8(Qb + (size_t)(t0 + l31) * 32 + 16 + hi * 8);
        f32x16 st = MFMA32(a0, q0, z16);
        st = MFMA32(a1, q1, st);
        if (t0 == sbase) {
#pragma unroll
            for (int r = 0; r < 16; ++r) {
                int s_local = (r & 3) + 8 * (r >> 2) + 4 * hi;
                acc[r] += (l31 >= s_local) ? exp2f(st[r]) : 0.f;
            }
        } else {
#pragma unroll
            for (int r = 0; r < 16; ++r) acc[r] += exp2f(st[r]);
        }
    }
#pragma unroll
    for (int off = 1; off <= 16; off <<= 1)
#pragma unroll
        for (int r = 0; r < 16; ++r) acc[r] += __shfl_xor(acc[r], off, 64);
    if (l31 == 0) {
#pragma unroll
        for (int r = 0; r < 16; ++r) {
            int s_local = (r & 3) + 8 * (r >> 2) + 4 * hi;
            colL[(size_t)bh * TT + sbase + s_local] = acc[r];
        }
    }
}

// ---------------------------------------------------------------------------
// Scale+transpose V: Vt[bh][d][s] = Vf[bh][s][d] / L_s   (bf16)
__global__ __launch_bounds__(256) void scale_v(const float* __restrict__ Vf,
                                               const float* __restrict__ colL,
                                               unsigned short* __restrict__ Vt) {
    __shared__ float tile[64][33];
    int bh = blockIdx.y, s0 = blockIdx.x * 64, tid = threadIdx.x;
    int r = tid >> 2, c4 = (tid & 3) * 8;
    float rl = 1.0f / colL[(size_t)bh * TT + s0 + r];
    const float* src = &Vf[((size_t)bh * TT + s0 + r) * 32 + c4];
    float4 v0 = *(const float4*)src;
    float4 v1 = *(const float4*)(src + 4);
    tile[r][c4 + 0] = v0.x * rl; tile[r][c4 + 1] = v0.y * rl;
    tile[r][c4 + 2] = v0.z * rl; tile[r][c4 + 3] = v0.w * rl;
    tile[r][c4 + 4] = v1.x * rl; tile[r][c4 + 5] = v1.y * rl;
    tile[r][c4 + 6] = v1.z * rl; tile[r][c4 + 7] = v1.w * rl;
    __syncthreads();
    int d = tid >> 3, sl = (tid & 7) * 8;
    u16x8 o;
#pragma unroll
    for (int i = 0; i < 8; ++i) o[i] = f2b(tile[sl + i][d]);
    *(u16x8*)&Vt[((size_t)bh * 32 + d) * TT + s0 + sl] = o;
}

// ---------------------------------------------------------------------------
// Pass 2: O[t,:] = sum_{s<=t} exp2(q_t.k_s) * V'[s,:], xh = bf16(xn + O).
// Wave-private: 32 t-rows/wave, S^T=K.Q^T (C-layout cols=t -> packed b64 LDS
// writes), PV via 16x16x32 A-frag read back (b128). No __syncthreads at all.
__global__ __launch_bounds__(256) void attn_out(const unsigned short* __restrict__ Qbf,
                                                const unsigned short* __restrict__ Kbf,
                                                const unsigned short* __restrict__ Vt,
                                                const float* __restrict__ xn,
                                                unsigned short* __restrict__ xh_bf) {
    __shared__ unsigned short Pt[128][40];   // [t_block][s_chunk 0..31 +pad]
    int tid = threadIdx.x;
    int w = tid >> 6, lane = tid & 63, q = lane >> 4, col = lane & 15;
    int bh = blockIdx.y, b = bh >> 3, h = bh & 7;
    int tbase = blockIdx.x * 128 + w * 32;
    int trow = w * 32;
    const unsigned short* Qrow = Qbf + ((size_t)bh * TT + tbase) * 32;
    const unsigned short* Kb = Kbf + (size_t)bh * TT * 32;
    const unsigned short* Vb = Vt + (size_t)bh * 32 * TT;
    bf16x8 q0 = ld8(Qrow + (size_t)col * 32 + q * 8);          // t 0..15
    bf16x8 q1 = ld8(Qrow + (size_t)(16 + col) * 32 + q * 8);   // t 16..31
    const f32x4 z = {};
    f32x4 o00 = z, o01 = z, o10 = z, o11 = z;   // [tsub][dsub]

    for (int s0 = 0; s0 <= tbase; s0 += 32) {
        bf16x8 k0 = ld8(Kb + (size_t)(s0 + col) * 32 + q * 8);        // s 0..15
        bf16x8 k1 = ld8(Kb + (size_t)(s0 + 16 + col) * 32 + q * 8);   // s 16..31
        // S^T tiles: [ssub][tsub], C-layout col=t_local, row=q*4+r=s_local
        f32x4 st00 = MFMA16(k0, q0, z);
        f32x4 st01 = MFMA16(k0, q1, z);
        f32x4 st10 = MFMA16(k1, q0, z);
        f32x4 st11 = MFMA16(k1, q1, z);
        if (s0 == tbase) {   // diagonal chunk: mask s_g <= t_g
            float e[4][4];   // [ssub*2+tsub][r]
#pragma unroll
            for (int r = 0; r < 4; ++r) {
                int sl0 = q * 4 + r, sl1 = 16 + q * 4 + r;
                e[0][r] = (sl0 <= col)      ? exp2f(st00[r]) : 0.f;  // t 0..15
                e[1][r] = 1.f ? exp2f(st01[r]) : 0.f;                // s<16<=t: full
                e[2][r] = (sl1 <= col)      ? exp2f(st10[r]) : 0.f;  // mostly 0
                e[3][r] = (sl1 <= 16 + col) ? exp2f(st11[r]) : 0.f;
            }
            uint2 w0, w1, w2, w3;
            w0.x = pk_bf16(e[0][0], e[0][1]); w0.y = pk_bf16(e[0][2], e[0][3]);
            w1.x = pk_bf16(e[1][0], e[1][1]); w1.y = pk_bf16(e[1][2], e[1][3]);
            w2.x = pk_bf16(e[2][0], e[2][1]); w2.y = pk_bf16(e[2][2], e[2][3]);
            w3.x = pk_bf16(e[3][0], e[3][1]); w3.y = pk_bf16(e[3][2], e[3][3]);
            *(uint2*)&Pt[trow + col][q * 4]           = w0;
            *(uint2*)&Pt[trow + 16 + col][q * 4]      = w1;
            *(uint2*)&Pt[trow + col][16 + q * 4]      = w2;
            *(uint2*)&Pt[trow + 16 + col][16 + q * 4] = w3;
        } else {
            uint2 w0, w1, w2, w3;
            w0.x = pk_bf16(exp2f(st00[0]), exp2f(st00[1]));
            w0.y = pk_bf16(exp2f(st00[2]), exp2f(st00[3]));
            w1.x = pk_bf16(exp2f(st01[0]), exp2f(st01[1]));
            w1.y = pk_bf16(exp2f(st01[2]), exp2f(st01[3]));
            w2.x = pk_bf16(exp2f(st10[0]), exp2f(st10[1]));
            w2.y = pk_bf16(exp2f(st10[2]), exp2f(st10[3]));
            w3.x = pk_bf16(exp2f(st11[0]), exp2f(st11[1]));
            w3.y = pk_bf16(exp2f(st11[2]), exp2f(st11[3]));
            *(uint2*)&Pt[trow + col][q * 4]           = w0;
            *(uint2*)&Pt[trow + 16 + col][q * 4]      = w1;
            *(uint2*)&Pt[trow + col][16 + q * 4]      = w2;
            *(uint2*)&Pt[trow + 16 + col][16 + q * 4] = w3;
        }
        // PV: A = P-frag (m=t, k=s from LDS), B = V'-frag (k=s, n=d)
        bf16x8 p0 = ld8(&Pt[trow + col][q * 8]);
        bf16x8 p1 = ld8(&Pt[trow + 16 + col][q * 8]);
        bf16x8 v0 = ld8(Vb + (size_t)col * TT + s0 + q * 8);          // d 0..15
        bf16x8 v1 = ld8(Vb + (size_t)(16 + col) * TT + s0 + q * 8);   // d 16..31
        o00 = MFMA16(p0, v0, o00);
        o01 = MFMA16(p0, v1, o01);
        o10 = MFMA16(p1, v0, o10);
        o11 = MFMA16(p1, v1, o11);
    }

    // Epilogue: C-layout col=d_local, row=q*4+r=t_local; xh = xn + O
#pragma unroll
    for (int r = 0; r < 4; ++r) {
        int t0g = tbase + q * 4 + r;
        int t1g = tbase + 16 + q * 4 + r;
        size_t i00 = ((size_t)(b * TT) + t0g) * TE + h * 32 + col;
        size_t i10 = ((size_t)(b * TT) + t1g) * TE + h * 32 + col;
        xh_bf[i00]      = f2b(o00[r] + xn[i00]);
        xh_bf[i00 + 16] = f2b(o01[r] + xn[i00 + 16]);
        xh_bf[i10]      = f2b(o10[r] + xn[i10]);
        xh_bf[i10 + 16] = f2b(o11[r] + xn[i10 + 16]);
    }
}

// ---------------------------------------------------------------------------
extern "C" void kernel_launch(void* const* d_in, const int* in_sizes, int n_in,
                              void* d_out, int out_size, void* d_ws, size_t ws_size,
                              hipStream_t stream) {
    (void)in_sizes; (void)n_in; (void)out_size; (void)ws_size;
    const float* x     = (const float*)d_in[0];
    const float* wq    = (const float*)d_in[1];
    const float* wk    = (const float*)d_in[2];
    const float* wv    = (const float*)d_in[3];
    const float* w_lin = (const float*)d_in[4];
    const float* b_lin = (const float*)d_in[5];
    const float* g1    = (const float*)d_in[6];
    const float* beta1 = (const float*)d_in[7];
    const float* g2    = (const float*)d_in[8];
    const float* beta2 = (const float*)d_in[9];
    const float* w_f1  = (const float*)d_in[10];
    const float* b_f1  = (const float*)d_in[11];
    const float* w_f2  = (const float*)d_in[12];
    const float* b_f2  = (const float*)d_in[13];
    float* out = (float*)d_out;

    char* ws = (char*)d_ws;
    unsigned short* Wqkv_t = (unsigned short*)(ws + 0);         //  384 KB
    unsigned short* Wlin_t = (unsigned short*)(ws + 393216);    //  128 KB
    unsigned short* Wf1_t  = (unsigned short*)(ws + 524288);    //  512 KB
    unsigned short* Wf2_t  = (unsigned short*)(ws + 1048576);   //  512 KB
    float*          xn     = (float*)(ws + 1572864);            //   16 MB  [xl aliases]
    unsigned short* xn_bf  = (unsigned short*)(ws + 18350080);  //    8 MB  [x2_bf aliases]
    unsigned short* Qbf    = (unsigned short*)(ws + 26738688);  //    8 MB ┐
    unsigned short* Kbf    = (unsigned short*)(ws + 35127296);  //    8 MB ├ h_bf aliases (32 MB)
    unsigned short* Vt     = (unsigned short*)(ws + 43515904);  //    8 MB │
    unsigned short* xh_bf  = (unsigned short*)(ws + 51904512);  //    8 MB ┘
    float*          Vf     = (float*)(ws + 60293120);           //   16 MB  [x2 aliases]
    float*          colL   = (float*)(ws + 77070336);           //  512 KB
    float*          xl     = xn;
    unsigned short* x2_bf  = xn_bf;
    unsigned short* h_bf   = Qbf;
    float*          x2     = Vf;

    conv_w<<<3072, 256, 0, stream>>>(wq, wk, wv, w_lin, w_f1, w_f2,
                                     Wqkv_t, Wlin_t, Wf1_t, Wf2_t);
    ln_w<<<4096, 256, 0, stream>>>(x, g1, beta1, xn, xn_bf);
    gemm_qkv<<<dim3(12, 128), 256, 0, stream>>>(xn_bf, Wqkv_t, Qbf, Kbf, Vf);
    attn_cols<<<dim3(16, 64), 256, 0, stream>>>(Qbf, Kbf, colL);
    scale_v<<<dim3(32, 64), 256, 0, stream>>>(Vf, colL, Vt);
    attn_out<<<dim3(16, 64), 256, 0, stream>>>(Qbf, Kbf, Vt, xn, xh_bf);
    gemm_bf16<<<dim3(4, 128), 256, 0, stream>>>(xh_bf, Wlin_t, b_lin, nullptr,
                                                xl, nullptr, 256, 256, 0);
    ln_w<<<4096, 256, 0, stream>>>(xl, g2, beta2, x2, x2_bf);
    gemm_bf16<<<dim3(16, 128), 256, 0, stream>>>(x2_bf, Wf1_t, b_f1, nullptr,
                                                 nullptr, h_bf, 1024, 256, 1);
    gemm_bf16<<<dim3(4, 128), 256, 0, stream>>>(h_bf, Wf2_t, b_f2, x2,
                                                out, nullptr, 256, 1024, 0);
}

// Round 4
// 378.916 us; speedup vs baseline: 5.0078x; 1.2374x over previous
//
#include <hip/hip_runtime.h>
#include <math.h>

// B=8, T=2048, E=256, H=8, D=32, F=1024
#define TT 2048
#define TE 256
// Q pre-scale: 256^-0.5 * log2(e)  (so softmax exp == exp2 of scores)
#define QSCALE (0.0625f * 1.44269504088896f)

typedef short  bf16x8 __attribute__((ext_vector_type(8)));
typedef float  f32x4  __attribute__((ext_vector_type(4)));
typedef float  f32x16 __attribute__((ext_vector_type(16)));
typedef unsigned short u16x4 __attribute__((ext_vector_type(4)));
typedef unsigned short u16x8 __attribute__((ext_vector_type(8)));

__device__ __forceinline__ unsigned short f2b(float f) {
    union { float f; unsigned int u; } v; v.f = f;
    unsigned int r = v.u + 0x7FFF + ((v.u >> 16) & 1);   // RNE
    return (unsigned short)(r >> 16);
}
__device__ __forceinline__ float b2f(unsigned short u) {
    union { unsigned int i; float f; } v; v.i = ((unsigned int)u) << 16;
    return v.f;
}
__device__ __forceinline__ unsigned int pk_bf16(float a, float b) {
    return (unsigned int)f2b(a) | ((unsigned int)f2b(b) << 16);
}
#if defined(__has_builtin)
#if __has_builtin(__builtin_amdgcn_exp2f)
#define FEXP2(x) __builtin_amdgcn_exp2f(x)
#else
#define FEXP2(x) exp2f(x)
#endif
#else
#define FEXP2(x) exp2f(x)
#endif
__device__ __forceinline__ bf16x8 ld8(const unsigned short* p) {
    return *(const bf16x8*)p;
}
#define MFMA16(a, b, c) __builtin_amdgcn_mfma_f32_16x16x32_bf16((a), (b), (c), 0, 0, 0)
#define MFMA32(a, b, c) __builtin_amdgcn_mfma_f32_32x32x16_bf16((a), (b), (c), 0, 0, 0)

// ---------------------------------------------------------------------------
// Weight convert/transpose to bf16 [N][K] row-major
__global__ __launch_bounds__(256) void conv_w(const float* __restrict__ wq,
                                              const float* __restrict__ wk,
                                              const float* __restrict__ wv,
                                              const float* __restrict__ w_lin,
                                              const float* __restrict__ w_f1,
                                              const float* __restrict__ w_f2,
                                              unsigned short* __restrict__ Wqkv,
                                              unsigned short* __restrict__ Wlin,
                                              unsigned short* __restrict__ Wf1,
                                              unsigned short* __restrict__ Wf2) {
    int idx = blockIdx.x * 256 + threadIdx.x;
    if (idx < 196608) {                       // Wqkv_t [768][256]
        int n = idx >> 8, k = idx & 255;
        int which = n >> 8, h = (n >> 5) & 7, d = n & 31;
        const float* w = (which == 0) ? wq : (which == 1) ? wk : wv;
        Wqkv[idx] = f2b(w[(h * 256 + k) * 32 + d]);
    } else if (idx < 262144) {                // Wlin_t [256][256]
        int i = idx - 196608; int n = i >> 8, k = i & 255;
        Wlin[i] = f2b(w_lin[k * 256 + n]);
    } else if (idx < 524288) {                // Wf1_t [1024][256]
        int i = idx - 262144; int n = i >> 8, k = i & 255;
        Wf1[i] = f2b(w_f1[k * 1024 + n]);
    } else {                                  // Wf2_t [256][1024]
        int i = idx - 524288; int n = i >> 10, k = i & 1023;
        Wf2[i] = f2b(w_f2[k * 256 + n]);
    }
}

// ---------------------------------------------------------------------------
// LayerNorm, wave-per-row (E=256 = 64 lanes x float4), shuffle reduce, no LDS
__global__ __launch_bounds__(256) void ln_w(const float* __restrict__ X,
                                            const float* __restrict__ g,
                                            const float* __restrict__ bta,
                                            float* __restrict__ Y,
                                            unsigned short* __restrict__ Yb) {
    int row = blockIdx.x * 4 + (threadIdx.x >> 6);
    int lane = threadIdx.x & 63;
    const float4 v = *(const float4*)&X[(size_t)row * TE + lane * 4];
    float s = v.x + v.y + v.z + v.w;
    float s2 = v.x * v.x + v.y * v.y + v.z * v.z + v.w * v.w;
#pragma unroll
    for (int off = 1; off <= 32; off <<= 1) {
        s  += __shfl_xor(s,  off, 64);
        s2 += __shfl_xor(s2, off, 64);
    }
    float mean = s * (1.0f / TE);
    float var = s2 * (1.0f / TE) - mean * mean;
    float rstd = rsqrtf(var + 1e-5f);
    const float4 gg = *(const float4*)&g[lane * 4];
    const float4 bb = *(const float4*)&bta[lane * 4];
    float4 o;
    o.x = (v.x - mean) * rstd * gg.x + bb.x;
    o.y = (v.y - mean) * rstd * gg.y + bb.y;
    o.z = (v.z - mean) * rstd * gg.z + bb.z;
    o.w = (v.w - mean) * rstd * gg.w + bb.w;
    if (Y) *(float4*)&Y[(size_t)row * TE + lane * 4] = o;
    if (Yb) {
        u16x4 ob = { f2b(o.x), f2b(o.y), f2b(o.z), f2b(o.w) };
        *(u16x4*)&Yb[(size_t)row * TE + lane * 4] = ob;
    }
}

// ---------------------------------------------------------------------------
// bf16 MFMA GEMM: C[M,N] = A[M,K] @ Wt[N,K]^T. 4 waves x 32 m-rows, 64 n.
__global__ __launch_bounds__(256) void gemm_bf16(const unsigned short* __restrict__ A,
                                                 const unsigned short* __restrict__ Bt,
                                                 const float* __restrict__ bias,
                                                 const float* __restrict__ resid,
                                                 float* __restrict__ outF,
                                                 unsigned short* __restrict__ outB,
                                                 int N, int K, int relu) {
    int tid = threadIdx.x;
    int w = tid >> 6, lane = tid & 63, q = lane >> 4, col = lane & 15;
    int m0 = blockIdx.y * 128 + w * 32;
    int n0 = blockIdx.x * 64;
    f32x4 acc[2][4] = {};
    const unsigned short* ar0 = A + (size_t)(m0 + col) * K + q * 8;
    const unsigned short* ar1 = ar0 + (size_t)16 * K;
    const unsigned short* bp0 = Bt + (size_t)(n0 + col) * K + q * 8;
    const unsigned short* bp1 = bp0 + (size_t)16 * K;
    const unsigned short* bp2 = bp0 + (size_t)32 * K;
    const unsigned short* bp3 = bp0 + (size_t)48 * K;
#pragma unroll 4
    for (int k0 = 0; k0 < K; k0 += 32) {
        bf16x8 a0 = ld8(ar0 + k0);
        bf16x8 a1 = ld8(ar1 + k0);
        bf16x8 b0 = ld8(bp0 + k0), b1 = ld8(bp1 + k0);
        bf16x8 b2 = ld8(bp2 + k0), b3 = ld8(bp3 + k0);
        acc[0][0] = MFMA16(a0, b0, acc[0][0]); acc[1][0] = MFMA16(a1, b0, acc[1][0]);
        acc[0][1] = MFMA16(a0, b1, acc[0][1]); acc[1][1] = MFMA16(a1, b1, acc[1][1]);
        acc[0][2] = MFMA16(a0, b2, acc[0][2]); acc[1][2] = MFMA16(a1, b2, acc[1][2]);
        acc[0][3] = MFMA16(a0, b3, acc[0][3]); acc[1][3] = MFMA16(a1, b3, acc[1][3]);
    }
#pragma unroll
    for (int i = 0; i < 2; ++i)
#pragma unroll
    for (int j = 0; j < 4; ++j) {
        int n = n0 + j * 16 + col;
#pragma unroll
        for (int r = 0; r < 4; ++r) {
            int m = m0 + i * 16 + q * 4 + r;
            float v = acc[i][j][r];
            if (bias) v += bias[n];
            if (relu) v = fmaxf(v, 0.f);
            if (resid) v += resid[(size_t)m * N + n];
            if (outF) outF[(size_t)m * N + n] = v;
            if (outB) outB[(size_t)m * N + n] = f2b(v);
        }
    }
}

// ---------------------------------------------------------------------------
// QKV GEMM. Epilogue scatter: Qbf (x QSCALE) and Kbf in [bh][t][32];
// V^T (unscaled bf16) in [bh][d][TT] with packed uint2 stores.
__global__ __launch_bounds__(256) void gemm_qkv(const unsigned short* __restrict__ A,
                                                const unsigned short* __restrict__ Bt,
                                                unsigned short* __restrict__ Qbf,
                                                unsigned short* __restrict__ Kbf,
                                                unsigned short* __restrict__ VtRaw) {
    const int K = 256;
    int tid = threadIdx.x;
    int w = tid >> 6, lane = tid & 63, q = lane >> 4, col = lane & 15;
    int m0 = blockIdx.y * 128 + w * 32;
    int n0 = blockIdx.x * 64;
    f32x4 acc[2][4] = {};
    const unsigned short* ar0 = A + (size_t)(m0 + col) * K + q * 8;
    const unsigned short* ar1 = ar0 + (size_t)16 * K;
    const unsigned short* bp0 = Bt + (size_t)(n0 + col) * K + q * 8;
#pragma unroll
    for (int k0 = 0; k0 < K; k0 += 32) {
        bf16x8 a0 = ld8(ar0 + k0);
        bf16x8 a1 = ld8(ar1 + k0);
        bf16x8 b0 = ld8(bp0 + k0), b1 = ld8(bp0 + 16 * K + k0);
        bf16x8 b2 = ld8(bp0 + 32 * K + k0), b3 = ld8(bp0 + 48 * K + k0);
        acc[0][0] = MFMA16(a0, b0, acc[0][0]); acc[1][0] = MFMA16(a1, b0, acc[1][0]);
        acc[0][1] = MFMA16(a0, b1, acc[0][1]); acc[1][1] = MFMA16(a1, b1, acc[1][1]);
        acc[0][2] = MFMA16(a0, b2, acc[0][2]); acc[1][2] = MFMA16(a1, b2, acc[1][2]);
        acc[0][3] = MFMA16(a0, b3, acc[0][3]); acc[1][3] = MFMA16(a1, b3, acc[1][3]);
    }
#pragma unroll
    for (int i = 0; i < 2; ++i)
#pragma unroll
    for (int j = 0; j < 4; ++j) {
        int n = n0 + j * 16 + col;
        int which = n >> 8, h = (n >> 5) & 7, d = n & 31;
        int m = m0 + i * 16 + q * 4;
        int b = m >> 11, t = m & 2047;
        int bh = b * 8 + h;
        if (which == 0) {
#pragma unroll
            for (int r = 0; r < 4; ++r)
                Qbf[((size_t)bh * TT + t + r) * 32 + d] = f2b(acc[i][j][r] * QSCALE);
        } else if (which == 1) {
#pragma unroll
            for (int r = 0; r < 4; ++r)
                Kbf[((size_t)bh * TT + t + r) * 32 + d] = f2b(acc[i][j][r]);
        } else {
            uint2 pv;
            pv.x = pk_bf16(acc[i][j][0], acc[i][j][1]);
            pv.y = pk_bf16(acc[i][j][2], acc[i][j][3]);
            *(uint2*)&VtRaw[((size_t)bh * 32 + d) * TT + t] = pv;
        }
    }
}

// ---------------------------------------------------------------------------
// Pass 1: colLinv[s] = 1 / sum_{t>=s} exp2(q_t . k_s). Balanced: wave u
// handles s-tiles {u, 63-u} (65 t-iterations total for every wave).
__global__ __launch_bounds__(256) void attn_cols(const unsigned short* __restrict__ Qbf,
                                                 const unsigned short* __restrict__ Kbf,
                                                 float* __restrict__ colLinv) {
    int tid = threadIdx.x;
    int w = tid >> 6, lane = tid & 63, hi = lane >> 5, l31 = lane & 31;
    int bh = blockIdx.y;
    int u = blockIdx.x * 4 + w;               // 0..31
    const unsigned short* Qb = Qbf + (size_t)bh * TT * 32;
    const unsigned short* Kb = Kbf + (size_t)bh * TT * 32;
    const f32x16 z16 = {};
#pragma unroll
    for (int phase = 0; phase < 2; ++phase) {
        int stile = phase ? (63 - u) : u;
        int sbase = stile * 32;
        bf16x8 a0 = ld8(Kb + (size_t)(sbase + l31) * 32 + hi * 8);        // d 0..15
        bf16x8 a1 = ld8(Kb + (size_t)(sbase + l31) * 32 + 16 + hi * 8);   // d 16..31
        float acc[16] = {};
        for (int t0 = sbase; t0 < TT; t0 += 32) {
            bf16x8 q0 = ld8(Qb + (size_t)(t0 + l31) * 32 + hi * 8);
            bf16x8 q1 = ld8(Qb + (size_t)(t0 + l31) * 32 + 16 + hi * 8);
            f32x16 st = MFMA32(a0, q0, z16);
            st = MFMA32(a1, q1, st);
            if (t0 == sbase) {
#pragma unroll
                for (int r = 0; r < 16; ++r) {
                    int s_local = (r & 3) + 8 * (r >> 2) + 4 * hi;
                    acc[r] += (l31 >= s_local) ? FEXP2(st[r]) : 0.f;
                }
            } else {
#pragma unroll
                for (int r = 0; r < 16; ++r) acc[r] += FEXP2(st[r]);
            }
        }
#pragma unroll
        for (int off = 1; off <= 16; off <<= 1)
#pragma unroll
            for (int r = 0; r < 16; ++r) acc[r] += __shfl_xor(acc[r], off, 64);
        if (l31 == 0) {
#pragma unroll
            for (int r = 0; r < 16; ++r) {
                int s_local = (r & 3) + 8 * (r >> 2) + 4 * hi;
                colLinv[(size_t)bh * TT + sbase + s_local] = 1.0f / acc[r];
            }
        }
    }
}

// ---------------------------------------------------------------------------
// Vt[bh][d][s] = VtRaw[bh][d][s] * colLinv[bh][s]; one block per (bh,d) row.
__global__ __launch_bounds__(256) void scale_vt(const unsigned short* __restrict__ VtRaw,
                                                const float* __restrict__ colLinv,
                                                unsigned short* __restrict__ Vt) {
    int bhd = blockIdx.x;            // bh*32 + d
    int bh = bhd >> 5;
    int s = threadIdx.x * 8;
    u16x8 v = *(const u16x8*)&VtRaw[(size_t)bhd * TT + s];
    const float4 i0 = *(const float4*)&colLinv[(size_t)bh * TT + s];
    const float4 i1 = *(const float4*)&colLinv[(size_t)bh * TT + s + 4];
    u16x8 o;
    o[0] = f2b(b2f(v[0]) * i0.x); o[1] = f2b(b2f(v[1]) * i0.y);
    o[2] = f2b(b2f(v[2]) * i0.z); o[3] = f2b(b2f(v[3]) * i0.w);
    o[4] = f2b(b2f(v[4]) * i1.x); o[5] = f2b(b2f(v[5]) * i1.y);
    o[6] = f2b(b2f(v[6]) * i1.z); o[7] = f2b(b2f(v[7]) * i1.w);
    *(u16x8*)&Vt[(size_t)bhd * TT + s] = o;
}

// ---------------------------------------------------------------------------
// Pass 2: O[t,:] = sum_{s<=t} exp2(q_t.k_s) * V'[s,:], xh = bf16(xn + O).
// Balanced: wave u handles t-tiles {u, 63-u} (65 chunks total per wave).
// Wave-private Pt (stride 36 ushorts: 72B rows -> <=2-way banks, 8B aligned),
// P read back as 2x b64. K/V prefetched one chunk ahead. No __syncthreads.
__global__ __launch_bounds__(256) void attn_out(const unsigned short* __restrict__ Qbf,
                                                const unsigned short* __restrict__ Kbf,
                                                const unsigned short* __restrict__ Vt,
                                                const float* __restrict__ xn,
                                                unsigned short* __restrict__ xh_bf) {
    __shared__ unsigned short Pt[128][36];
    int tid = threadIdx.x;
    int w = tid >> 6, lane = tid & 63, q = lane >> 4, col = lane & 15;
    int bh = blockIdx.y, b = bh >> 3, h = bh & 7;
    int u = blockIdx.x * 4 + w;               // 0..31
    int trow = w * 32;
    const unsigned short* Kb = Kbf + (size_t)bh * TT * 32;
    const unsigned short* Vb = Vt + (size_t)bh * 32 * TT;
    const f32x4 z = {};

#pragma unroll
    for (int phase = 0; phase < 2; ++phase) {
        int tt = phase ? (63 - u) : u;
        int tbase = tt * 32;
        const unsigned short* Qrow = Qbf + ((size_t)bh * TT + tbase) * 32;
        bf16x8 q0 = ld8(Qrow + (size_t)col * 32 + q * 8);          // t 0..15
        bf16x8 q1 = ld8(Qrow + (size_t)(16 + col) * 32 + q * 8);   // t 16..31
        f32x4 o00 = z, o01 = z, o10 = z, o11 = z;   // [tsub][dsub]

        bf16x8 ck0 = ld8(Kb + (size_t)col * 32 + q * 8);          // s 0..15
        bf16x8 ck1 = ld8(Kb + (size_t)(16 + col) * 32 + q * 8);   // s 16..31
        bf16x8 cv0 = ld8(Vb + (size_t)col * TT + q * 8);          // d 0..15
        bf16x8 cv1 = ld8(Vb + (size_t)(16 + col) * TT + q * 8);   // d 16..31

        for (int s0 = 0; s0 <= tbase; s0 += 32) {
            bool diag = (s0 == tbase);
            // S^T tiles: C-layout col=t_local, row=q*4+r=s_local
            f32x4 st00 = MFMA16(ck0, q0, z);
            f32x4 st01 = MFMA16(ck0, q1, z);
            f32x4 st11 = MFMA16(ck1, q1, z);
            f32x4 st10 = diag ? z : MFMA16(ck1, q0, z);
            // prefetch next chunk
            int sn = s0 + 32;
            if (sn <= tbase) {
                ck0 = ld8(Kb + (size_t)(sn + col) * 32 + q * 8);
                ck1 = ld8(Kb + (size_t)(sn + 16 + col) * 32 + q * 8);
            }
            uint2 w0, w1, w2, w3;
            if (diag) {   // mask s_g <= t_g
                float e0[4], e1[4], e3[4];
#pragma unroll
                for (int r = 0; r < 4; ++r) {
                    int sl = q * 4 + r;
                    e0[r] = (sl <= col) ? FEXP2(st00[r]) : 0.f;
                    e1[r] = FEXP2(st01[r]);              // s<16<=t: full
                    e3[r] = (sl <= col) ? FEXP2(st11[r]) : 0.f;
                }
                w0.x = pk_bf16(e0[0], e0[1]); w0.y = pk_bf16(e0[2], e0[3]);
                w1.x = pk_bf16(e1[0], e1[1]); w1.y = pk_bf16(e1[2], e1[3]);
                w2.x = 0u;                    w2.y = 0u;
                w3.x = pk_bf16(e3[0], e3[1]); w3.y = pk_bf16(e3[2], e3[3]);
            } else {
                w0.x = pk_bf16(FEXP2(st00[0]), FEXP2(st00[1]));
                w0.y = pk_bf16(FEXP2(st00[2]), FEXP2(st00[3]));
                w1.x = pk_bf16(FEXP2(st01[0]), FEXP2(st01[1]));
                w1.y = pk_bf16(FEXP2(st01[2]), FEXP2(st01[3]));
                w2.x = pk_bf16(FEXP2(st10[0]), FEXP2(st10[1]));
                w2.y = pk_bf16(FEXP2(st10[2]), FEXP2(st10[3]));
                w3.x = pk_bf16(FEXP2(st11[0]), FEXP2(st11[1]));
                w3.y = pk_bf16(FEXP2(st11[2]), FEXP2(st11[3]));
            }
            *(uint2*)&Pt[trow + col][q * 4]           = w0;
            *(uint2*)&Pt[trow + 16 + col][q * 4]      = w1;
            *(uint2*)&Pt[trow + col][16 + q * 4]      = w2;
            *(uint2*)&Pt[trow + 16 + col][16 + q * 4] = w3;
            // P A-frags: two 8B reads each (rows are 8B aligned at stride 36)
            union { uint2 u2[2]; bf16x8 v; } p0u, p1u;
            p0u.u2[0] = *(const uint2*)&Pt[trow + col][q * 8];
            p0u.u2[1] = *(const uint2*)&Pt[trow + col][q * 8 + 4];
            p1u.u2[0] = *(const uint2*)&Pt[trow + 16 + col][q * 8];
            p1u.u2[1] = *(const uint2*)&Pt[trow + 16 + col][q * 8 + 4];
            // PV
            o00 = MFMA16(p0u.v, cv0, o00);
            o01 = MFMA16(p0u.v, cv1, o01);
            o10 = MFMA16(p1u.v, cv0, o10);
            o11 = MFMA16(p1u.v, cv1, o11);
            if (sn <= tbase) {
                cv0 = ld8(Vb + (size_t)col * TT + sn + q * 8);
                cv1 = ld8(Vb + (size_t)(16 + col) * TT + sn + q * 8);
            }
        }

        // Epilogue: C-layout col=d_local, row=q*4+r=t_local; xh = xn + O
#pragma unroll
        for (int r = 0; r < 4; ++r) {
            int t0g = tbase + q * 4 + r;
            int t1g = tbase + 16 + q * 4 + r;
            size_t i00 = ((size_t)(b * TT) + t0g) * TE + h * 32 + col;
            size_t i10 = ((size_t)(b * TT) + t1g) * TE + h * 32 + col;
            xh_bf[i00]      = f2b(o00[r] + xn[i00]);
            xh_bf[i00 + 16] = f2b(o01[r] + xn[i00 + 16]);
            xh_bf[i10]      = f2b(o10[r] + xn[i10]);
            xh_bf[i10 + 16] = f2b(o11[r] + xn[i10 + 16]);
        }
    }
}

// ---------------------------------------------------------------------------
extern "C" void kernel_launch(void* const* d_in, const int* in_sizes, int n_in,
                              void* d_out, int out_size, void* d_ws, size_t ws_size,
                              hipStream_t stream) {
    (void)in_sizes; (void)n_in; (void)out_size; (void)ws_size;
    const float* x     = (const float*)d_in[0];
    const float* wq    = (const float*)d_in[1];
    const float* wk    = (const float*)d_in[2];
    const float* wv    = (const float*)d_in[3];
    const float* w_lin = (const float*)d_in[4];
    const float* b_lin = (const float*)d_in[5];
    const float* g1    = (const float*)d_in[6];
    const float* beta1 = (const float*)d_in[7];
    const float* g2    = (const float*)d_in[8];
    const float* beta2 = (const float*)d_in[9];
    const float* w_f1  = (const float*)d_in[10];
    const float* b_f1  = (const float*)d_in[11];
    const float* w_f2  = (const float*)d_in[12];
    const float* b_f2  = (const float*)d_in[13];
    float* out = (float*)d_out;

    char* ws = (char*)d_ws;
    unsigned short* Wqkv_t = (unsigned short*)(ws + 0);         //  384 KB
    unsigned short* Wlin_t = (unsigned short*)(ws + 393216);    //  128 KB
    unsigned short* Wf1_t  = (unsigned short*)(ws + 524288);    //  512 KB
    unsigned short* Wf2_t  = (unsigned short*)(ws + 1048576);   //  512 KB
    float*          xn     = (float*)(ws + 1572864);            //   16 MB  [xl aliases]
    unsigned short* xn_bf  = (unsigned short*)(ws + 18350080);  //    8 MB  [x2_bf aliases]
    unsigned short* Qbf    = (unsigned short*)(ws + 26738688);  //    8 MB ┐
    unsigned short* Kbf    = (unsigned short*)(ws + 35127296);  //    8 MB ├ h_bf aliases (32 MB)
    unsigned short* VtRaw  = (unsigned short*)(ws + 43515904);  //    8 MB │
    unsigned short* Vt     = (unsigned short*)(ws + 51904512);  //    8 MB ┘
    unsigned short* xh_bf  = (unsigned short*)(ws + 60293120);  //    8 MB
    float*          x2     = (float*)(ws + 68681728);           //   16 MB
    float*          colLinv= (float*)(ws + 85459072);           //  512 KB
    float*          xl     = xn;
    unsigned short* x2_bf  = xn_bf;
    unsigned short* h_bf   = Qbf;

    conv_w<<<3072, 256, 0, stream>>>(wq, wk, wv, w_lin, w_f1, w_f2,
                                     Wqkv_t, Wlin_t, Wf1_t, Wf2_t);
    ln_w<<<4096, 256, 0, stream>>>(x, g1, beta1, xn, xn_bf);
    gemm_qkv<<<dim3(12, 128), 256, 0, stream>>>(xn_bf, Wqkv_t, Qbf, Kbf, VtRaw);
    attn_cols<<<dim3(8, 64), 256, 0, stream>>>(Qbf, Kbf, colLinv);
    scale_vt<<<2048, 256, 0, stream>>>(VtRaw, colLinv, Vt);
    attn_out<<<dim3(8, 64), 256, 0, stream>>>(Qbf, Kbf, Vt, xn, xh_bf);
    gemm_bf16<<<dim3(4, 128), 256, 0, stream>>>(xh_bf, Wlin_t, b_lin, nullptr,
                                                xl, nullptr, 256, 256, 0);
    ln_w<<<4096, 256, 0, stream>>>(xl, g2, beta2, x2, x2_bf);
    gemm_bf16<<<dim3(16, 128), 256, 0, stream>>>(x2_bf, Wf1_t, b_f1, nullptr,
                                                 nullptr, h_bf, 1024, 256, 1);
    gemm_bf16<<<dim3(4, 128), 256, 0, stream>>>(h_bf, Wf2_t, b_f2, x2,
                                                out, nullptr, 256, 1024, 0);
}